// Round 3
// baseline (165.797 us; speedup 1.0000x reference)
//
#include <hip/hip_runtime.h>
#include <math.h>

#define Bn 4
#define Cn 64
#define On 64
#define Hn 128
#define Wn 128
#define HWn (Hn * Wn)

typedef __attribute__((ext_vector_type(8))) short s16x8;
typedef __attribute__((ext_vector_type(4))) float f32x4;

__device__ __forceinline__ unsigned short f2bf(float f) {
    unsigned u = __float_as_uint(f);
    u += 0x7fffu + ((u >> 16) & 1u);  // RTNE (finite values)
    return (unsigned short)(u >> 16);
}
__device__ __forceinline__ float bf2f(unsigned short u) {
    return __uint_as_float(((unsigned)u) << 16);
}

// ---------------------------------------------------------------------------
// Kernel 1: x [B,C,H,W] f32 -> xt [B,HW,C] bf16 (channels-last gathers)
// ---------------------------------------------------------------------------
__global__ __launch_bounds__(256) void transpose_x_kernel(const float* __restrict__ x,
                                                          ushort* __restrict__ xt) {
    __shared__ float tile[64][65];
    int b = blockIdx.y, hw0 = blockIdx.x * 64, t = threadIdx.x;
    int lane = t & 63, grp = t >> 6;
    const float* xb = x + (size_t)b * Cn * HWn;
#pragma unroll
    for (int i = 0; i < 16; ++i) {
        int c = grp * 16 + i;
        tile[lane][c] = xb[(size_t)c * HWn + hw0 + lane];  // coalesced along hw
    }
    __syncthreads();
    int hw = t & 63, c0 = (t >> 6) * 16;
    ushort* dst = xt + ((size_t)(b * HWn + hw0 + hw)) * Cn + c0;
    s16x8 p0, p1;
#pragma unroll
    for (int j = 0; j < 8; ++j) {
        p0[j] = (short)f2bf(tile[hw][c0 + j]);
        p1[j] = (short)f2bf(tile[hw][c0 + 8 + j]);
    }
    *(s16x8*)dst = p0;
    *(s16x8*)(dst + 8) = p1;
}

// ---------------------------------------------------------------------------
// Kernel 2: weights -> bf16, [k][oc][c] layouts.
// wdT: [9][64][64] from w_def; woT: [9][32][64] from w_off (oc 27..31 -> 0)
// ---------------------------------------------------------------------------
__global__ __launch_bounds__(256) void transpose_w_kernel(const float* __restrict__ wdef,
                                                          const float* __restrict__ woff,
                                                          ushort* __restrict__ wdT,
                                                          ushort* __restrict__ woT) {
    int idx = blockIdx.x * 256 + threadIdx.x;
    if (idx < 9 * 64 * 64) {
        int c = idx & 63, oc = (idx >> 6) & 63, k = idx >> 12;
        wdT[idx] = f2bf(wdef[(oc * 64 + c) * 9 + k]);
    } else if (idx < 9 * 64 * 64 + 9 * 32 * 64) {
        int i2 = idx - 9 * 64 * 64;
        int c = i2 & 63, oc = (i2 >> 6) & 31, k = i2 >> 11;
        woT[i2] = (oc < 27) ? f2bf(woff[(oc * 64 + c) * 9 + k]) : (ushort)0;
    }
}

// ---------------------------------------------------------------------------
// Mega kernel: one wave per block, 32 px (same row) x 64 oc.
// Phase 1: offset conv (MFMA, N=32, K=576) -> s_om[px][oc] via LDS transpose.
// Phase 2: deformable bilinear sampling -> register A-frags -> MFMA N=64 K=576.
// No staging LDS, no per-tap barriers; B-frags straight from L2-resident
// transposed weights. A-frag layout (verified R2): m=lane&15, k=(lane>>4)*8+j.
// C/D layout (verified R2): col=lane&15, row=(lane>>4)*4+reg.
// ---------------------------------------------------------------------------
__global__ __launch_bounds__(64) void mega_kernel(const float* __restrict__ feat,
                                                  const ushort* __restrict__ xt,
                                                  const ushort* __restrict__ woT,
                                                  const ushort* __restrict__ wdT,
                                                  const float* __restrict__ b_off,
                                                  const float* __restrict__ b_def,
                                                  float* __restrict__ out) {
    __shared__ __align__(16) float smem[64 * 37];  // s_om [32][33] / s_out [64][37]
    float* s_om = smem;
    float* s_out = smem;

    int l = threadIdx.x;
    int q = l >> 4, r = l & 15;
    int p0 = blockIdx.x * 32;
    int b = p0 >> 14;            // / HWn
    int rem = p0 & (HWn - 1);
    int h = rem >> 7;            // / Wn
    int w0 = rem & (Wn - 1);     // multiple of 32

    f32x4 zero = {0.f, 0.f, 0.f, 0.f};

    // ================= Phase 1: offset conv =================
    f32x4 acc2[2][2];
    acc2[0][0] = zero; acc2[0][1] = zero; acc2[1][0] = zero; acc2[1][1] = zero;

#pragma unroll 1
    for (int k = 0; k < 9; ++k) {
        int dy = k / 3 - 1, dx = k % 3 - 1;
        int y = h + dy;
        bool yv = (y >= 0) && (y < Hn);
        s16x8 af[2][2];
#pragma unroll
        for (int tile = 0; tile < 2; ++tile) {
            int xx = w0 + tile * 16 + r + dx;
            bool valid = yv && (xx >= 0) && (xx < Wn);
#pragma unroll
            for (int s = 0; s < 2; ++s) {
                const float* fp = feat + (((size_t)b * Cn + s * 32 + q * 8) * HWn + y * Wn + xx);
                s16x8 p;
#pragma unroll
                for (int j = 0; j < 8; ++j) {
                    float v = valid ? fp[(size_t)j * HWn] : 0.f;
                    p[j] = (short)f2bf(v);
                }
                af[tile][s] = p;
            }
        }
#pragma unroll
        for (int s = 0; s < 2; ++s) {
            int co = s * 32 + q * 8;
#pragma unroll
            for (int ot = 0; ot < 2; ++ot) {
                s16x8 bw = *(const s16x8*)(woT + ((k * 32 + ot * 16 + r) * 64 + co));
                acc2[0][ot] = __builtin_amdgcn_mfma_f32_16x16x32_bf16(af[0][s], bw, acc2[0][ot], 0, 0, 0);
                acc2[1][ot] = __builtin_amdgcn_mfma_f32_16x16x32_bf16(af[1][s], bw, acc2[1][ot], 0, 0, 0);
            }
        }
    }
    // bias + sigmoid(mask planes), redistribute via LDS: s_om[px][oc]
#pragma unroll
    for (int tile = 0; tile < 2; ++tile)
#pragma unroll
        for (int ot = 0; ot < 2; ++ot) {
            int oc = ot * 16 + r;
            float bo = (oc < 27) ? b_off[oc] : 0.f;
#pragma unroll
            for (int reg = 0; reg < 4; ++reg) {
                int px = tile * 16 + q * 4 + reg;
                float v = acc2[tile][ot][reg] + bo;
                if (oc >= 18 && oc < 27) v = 1.f / (1.f + __expf(-v));
                s_om[px * 33 + oc] = v;
            }
        }
    __syncthreads();

    // ================= Phase 2: sampling + main GEMM =================
    f32x4 acc[2][4];
#pragma unroll
    for (int i = 0; i < 4; ++i) { acc[0][i] = zero; acc[1][i] = zero; }

    const int bb = b * HWn * Cn;

#pragma unroll 1
    for (int k = 0; k < 9; ++k) {
        int dy = k / 3 - 1, dx = k % 3 - 1;
        s16x8 af[2][2];
#pragma unroll
        for (int tile = 0; tile < 2; ++tile) {
            int px = tile * 16 + r;
            float offx = s_om[px * 33 + k];
            float offy = s_om[px * 33 + 9 + k];
            float mv   = s_om[px * 33 + 18 + k];
            float ys = (float)(h + dy) + offy;
            float xs = (float)(w0 + px + dx) + offx;
            float y0f = floorf(ys), x0f = floorf(xs);
            float fy = ys - y0f, fx = xs - x0f;
            int y0 = (int)y0f, x0 = (int)x0f;
            float g[4];
            int a[4];
#pragma unroll
            for (int n = 0; n < 4; ++n) {
                int yy = y0 + (n >> 1), xx = x0 + (n & 1);
                bool valid = (yy >= 0) && (yy < Hn) && (xx >= 0) && (xx < Wn);
                float wgt = ((n >> 1) ? fy : 1.f - fy) * ((n & 1) ? fx : 1.f - fx) * mv;
                g[n] = valid ? wgt : 0.f;
                int yc = min(max(yy, 0), Hn - 1), xc = min(max(xx, 0), Wn - 1);
                a[n] = bb + (yc * Wn + xc) * Cn;
            }
#pragma unroll
            for (int s = 0; s < 2; ++s) {
                int c = s * 32 + q * 8;
                s16x8 q0 = *(const s16x8*)(xt + a[0] + c);
                s16x8 q1 = *(const s16x8*)(xt + a[1] + c);
                s16x8 q2 = *(const s16x8*)(xt + a[2] + c);
                s16x8 q3 = *(const s16x8*)(xt + a[3] + c);
                s16x8 p;
#pragma unroll
                for (int j = 0; j < 8; ++j) {
                    float rr = g[0] * bf2f((unsigned short)q0[j])
                             + g[1] * bf2f((unsigned short)q1[j])
                             + g[2] * bf2f((unsigned short)q2[j])
                             + g[3] * bf2f((unsigned short)q3[j]);
                    p[j] = (short)f2bf(rr);
                }
                af[tile][s] = p;
            }
        }
#pragma unroll
        for (int s = 0; s < 2; ++s) {
            int co = s * 32 + q * 8;
#pragma unroll
            for (int ot = 0; ot < 4; ++ot) {
                s16x8 bw = *(const s16x8*)(wdT + ((k * 64 + ot * 16 + r) * 64 + co));
                acc[0][ot] = __builtin_amdgcn_mfma_f32_16x16x32_bf16(af[0][s], bw, acc[0][ot], 0, 0, 0);
                acc[1][ot] = __builtin_amdgcn_mfma_f32_16x16x32_bf16(af[1][s], bw, acc[1][ot], 0, 0, 0);
            }
        }
    }
    __syncthreads();  // done reading s_om; smem reused as s_out

    // ================= Epilogue: bias + ReLU, coalesced store =================
#pragma unroll
    for (int tile = 0; tile < 2; ++tile)
#pragma unroll
        for (int ot = 0; ot < 4; ++ot) {
            int oc = ot * 16 + r;
            float bv = b_def[oc];
#pragma unroll
            for (int reg = 0; reg < 4; ++reg) {
                int px = tile * 16 + q * 4 + reg;
                s_out[oc * 37 + px] = fmaxf(acc[tile][ot][reg] + bv, 0.f);
            }
        }
    __syncthreads();
    {
        float* ob = out + ((size_t)b * On) * HWn + h * Wn + w0;
        int px = l & 31, oh = l >> 5;
#pragma unroll
        for (int j = 0; j < 32; ++j) {
            int oc = j * 2 + oh;
            ob[(size_t)oc * HWn + px] = s_out[oc * 37 + px];
        }
    }
}

// ---------------------------------------------------------------------------
extern "C" void kernel_launch(void* const* d_in, const int* in_sizes, int n_in,
                              void* d_out, int out_size, void* d_ws, size_t ws_size,
                              hipStream_t stream) {
    const float* x = (const float*)d_in[0];
    const float* feat = (const float*)d_in[1];
    const float* w_off = (const float*)d_in[2];
    const float* b_off = (const float*)d_in[3];
    const float* w_def = (const float*)d_in[4];
    const float* b_def = (const float*)d_in[5];
    float* out = (float*)d_out;

    char* ws = (char*)d_ws;
    ushort* xt = (ushort*)ws;                          // 8 MB: [B,HW,C] bf16
    ushort* wdT = (ushort*)(ws + 8388608);             // 72 KB: [9,64,64] bf16
    ushort* woT = (ushort*)(ws + 8388608 + 73728);     // 36 KB: [9,32,64] bf16

    hipLaunchKernelGGL(transpose_x_kernel, dim3(HWn / 64, Bn), dim3(256), 0, stream, x, xt);
    hipLaunchKernelGGL(transpose_w_kernel, dim3(216), dim3(256), 0, stream, w_def, w_off, wdT, woT);
    hipLaunchKernelGGL(mega_kernel, dim3((Bn * HWn) / 32), dim3(64), 0, stream,
                       feat, xt, woT, wdT, b_off, b_def, out);
}